// Round 10
// baseline (288.196 us; speedup 1.0000x reference)
//
#include <hip/hip_runtime.h>
#include <hip/hip_bf16.h>
#include <cstdint>
#include <cstddef>

typedef unsigned short u16;
typedef short bf16x8 __attribute__((ext_vector_type(8)));
typedef float f32x4 __attribute__((ext_vector_type(4)));

constexpr int Ns = 512;   // N
constexpr int Dd = 128;   // D
constexpr int Cc = 128;   // C
#define EPSV 1e-5f

__device__ __forceinline__ u16 f2bf(float f){
    __hip_bfloat16 h = __float2bfloat16(f);
    return *reinterpret_cast<u16*>(&h);
}
__device__ __forceinline__ float bf2f(u16 h){
    return __uint_as_float(((uint32_t)h) << 16);
}
__device__ __forceinline__ float sigmoidf_(float x){
    return __builtin_amdgcn_rcpf(1.0f + __expf(-x));   // ~1ulp, fine at bf16
}

// same-wave LDS write->read ordering fence (guide rule #18)
#define LDS_FENCE do {                                         \
    asm volatile("s_waitcnt lgkmcnt(0)" ::: "memory");         \
    __builtin_amdgcn_sched_barrier(0);                         \
} while (0)

// ---------------------------------------------------------------------------
// K0: weights -> bf16, transposed [n][k].  Order: Wl,Wlg,Wr,Wrg,Wog,Wo
// ---------------------------------------------------------------------------
__global__ void k_prep(const float* __restrict__ Wl, const float* __restrict__ Wlg,
                       const float* __restrict__ Wr, const float* __restrict__ Wrg,
                       const float* __restrict__ Wog, const float* __restrict__ Wo,
                       u16* __restrict__ Wt){
    int idx = blockIdx.x * 256 + threadIdx.x;
    if (idx >= 6 * 16384) return;
    int m = idx >> 14; int nk = idx & 16383; int n = nk >> 7; int k = nk & 127;
    const float* W = (m == 0) ? Wl : (m == 1) ? Wlg : (m == 2) ? Wr
                   : (m == 3) ? Wrg : (m == 4) ? Wog : Wo;
    Wt[idx] = f2bf(W[k * Cc + n]);
}

// ---------------------------------------------------------------------------
// K1: LN(x) then 5 GEMMs.  128x128 output tile per block, 512 thr / 8 waves
// (wave = row-half h = w>>2 [64 rows] x col-quarter wq = w&3 [32 cols]).
// Per-wave structure identical to R9 (verified formulas), 2x fewer blocks ->
// prologue (x latency, LN, barriers) amortized 2x; weight L2 traffic halved.
// Rows map: local row lr in [0,128): a_loc = lr & 15, b_loc = lr >> 4.
// left/right k-blocked [c][a/8][b][a%8]; wave-private staging + 64B-segment
// coalesced stores.  og: block staging + int4 stores.
// ---------------------------------------------------------------------------
__global__ __launch_bounds__(512) void k1(
    const float* __restrict__ x, const float* __restrict__ g_ln, const float* __restrict__ b_ln,
    const u16* __restrict__ Wt,
    const float* __restrict__ bl, const float* __restrict__ blg,
    const float* __restrict__ br, const float* __restrict__ brg,
    const float* __restrict__ bog,
    u16* __restrict__ left, u16* __restrict__ right, u16* __restrict__ og)
{
    __shared__ u16  SB[17408];         // aliased: xn [128][136] / wp-stage [8][32][68] / og [128][132]
    __shared__ float gln[128], bln[128];

    const int t   = threadIdx.x;
    const int bid = blockIdx.x;
    const int a0  = (bid >> 6) << 4;   // 16 a's per block
    const int b0  = (bid & 63) << 3;   // 8 b's per block
    const int w = t >> 6, l = t & 63;
    const int lrow = l & 15, g = l >> 4;
    const int h  = w >> 2;             // row half (0/1)
    const int nb = (w & 3) * 32;       // col quarter
    const int orow = g << 2;
    const int kb2 = a0 >> 3;           // first of the block's two k-blocks

    // ---- prologue: x loads, LN stats, normalize into SB-as-xn [128][136] ----
    const int r = t >> 2, q = t & 3;   // r in [0,128): 4 threads per row
    const int aa = a0 + (r & 15), bb = b0 + (r >> 4);
    const float4* xrow = reinterpret_cast<const float4*>(x + ((size_t)aa * Ns + bb) * Dd);
    float4 xv[8];
#pragma unroll
    for (int i2 = 0; i2 < 8; ++i2) xv[i2] = xrow[q + 4 * i2];
    if (t < 128){ gln[t] = g_ln[t]; bln[t] = b_ln[t]; }

    float s1 = 0.f, s2 = 0.f;
#pragma unroll
    for (int i2 = 0; i2 < 8; ++i2){
        float4 v = xv[i2];
        s1 += v.x + v.y + v.z + v.w;
        s2 += v.x * v.x + v.y * v.y + v.z * v.z + v.w * v.w;
    }
    s1 += __shfl_xor(s1, 1); s1 += __shfl_xor(s1, 2);
    s2 += __shfl_xor(s2, 1); s2 += __shfl_xor(s2, 2);
    const float mm  = s1 * (1.0f / 128.0f);
    const float rsv = rsqrtf(s2 * (1.0f / 128.0f) - mm * mm + EPSV);
    __syncthreads();                   // (1) gln/bln ready
#pragma unroll
    for (int i2 = 0; i2 < 8; ++i2){
        const int d = (q + 4 * i2) * 4;
        ushort4 o;
        o.x = f2bf((xv[i2].x - mm) * rsv * gln[d + 0] + bln[d + 0]);
        o.y = f2bf((xv[i2].y - mm) * rsv * gln[d + 1] + bln[d + 1]);
        o.z = f2bf((xv[i2].z - mm) * rsv * gln[d + 2] + bln[d + 2]);
        o.w = f2bf((xv[i2].w - mm) * rsv * gln[d + 3] + bln[d + 3]);
        *reinterpret_cast<ushort4*>(&SB[r * 136 + d]) = o;
    }
    __syncthreads();                   // (2) xn ready

    // ---- A-fragments once: wave's 64 rows (h*64 + rf*16 + lrow) ----
    bf16x8 af[4][4];
#pragma unroll
    for (int ks = 0; ks < 4; ++ks)
#pragma unroll
        for (int rf = 0; rf < 4; ++rf)
            af[ks][rf] = *reinterpret_cast<const bf16x8*>(
                &SB[(h * 64 + rf * 16 + lrow) * 136 + ks * 32 + g * 8]);
    __syncthreads();                   // (3) all af reads done; SB free

    u16* SBw = &SB[w * 32 * 68];       // wave-private staging (32 cols x 68)
    const f32x4 zero4 = {0.f, 0.f, 0.f, 0.f};
    f32x4 aV[4], aG[4];

    auto GEMM1 = [&](const u16* WV, const u16* WG, int cf){
        const int col = nb + cf * 16 + lrow;
#pragma unroll
        for (int rf = 0; rf < 4; ++rf){ aV[rf] = zero4; aG[rf] = zero4; }
#pragma unroll
        for (int ks = 0; ks < 4; ++ks){
            bf16x8 bv = *reinterpret_cast<const bf16x8*>(WV + (size_t)col * 128 + ks * 32 + g * 8);
            bf16x8 bg = *reinterpret_cast<const bf16x8*>(WG + (size_t)col * 128 + ks * 32 + g * 8);
#pragma unroll
            for (int rf = 0; rf < 4; ++rf)
                aV[rf] = __builtin_amdgcn_mfma_f32_16x16x32_bf16(af[ks][rf], bv, aV[rf], 0, 0, 0);
#pragma unroll
            for (int rf = 0; rf < 4; ++rf)
                aG[rf] = __builtin_amdgcn_mfma_f32_16x16x32_bf16(af[ks][rf], bg, aG[rf], 0, 0, 0);
        }
    };
    // gate + stage into wave-private SBw[cl2][local_row]  (local_row = rf*16+orow+j)
    auto STW = [&](const float* bV, const float* bG, int cf){
        const int cl2 = cf * 16 + lrow;
        const int col = nb + cl2;
        const float bVv = bV[col], bGv = bG[col];
#pragma unroll
        for (int rf = 0; rf < 4; ++rf){
            ushort4 pk;
#pragma unroll
            for (int j = 0; j < 4; ++j){
                const float vv = aV[rf][j] + bVv;
                const float gg = aG[rf][j] + bGv;
                ((u16*)&pk)[j] = f2bf(sigmoidf_(gg) * vv);
            }
            *reinterpret_cast<ushort4*>(&SBw[cl2 * 68 + rf * 16 + orow]) = pk;
        }
    };
    // readback: local_row = b_rel*16 + kbi*8 + s  (b_rel = rf; a = orow+j):
    // segment (col, kbi): 4 b_rel x 8 a%8 = 32 u16; one int4 per (col,kbi,b_rel)
    auto STORE = [&](u16* dst){
#pragma unroll
        for (int it = 0; it < 4; ++it){
            const int idx   = it * 64 + l;           // 0..255
            const int col_l = idx >> 3;              // 0..31
            const int kbi   = (idx >> 2) & 1;
            const int b_rel = idx & 3;
            int4 v = *reinterpret_cast<const int4*>(&SBw[col_l * 68 + b_rel * 16 + kbi * 8]);
            const size_t base = (((size_t)(nb + col_l) * 64 + kb2 + kbi) * Ns
                                 + b0 + h * 4 + b_rel) * 8;
            *reinterpret_cast<int4*>(dst + base) = v;
        }
    };

    // ---- L/R pipeline (wave-private; fences order same-wave LDS reuse) ----
    GEMM1(Wt,             Wt + 16384,     0); STW(bl, blg, 0);
    GEMM1(Wt,             Wt + 16384,     1); STW(bl, blg, 1);
    LDS_FENCE;
    STORE(left);
    LDS_FENCE;
    GEMM1(Wt + 2 * 16384, Wt + 3 * 16384, 0); STW(br, brg, 0);
    GEMM1(Wt + 2 * 16384, Wt + 3 * 16384, 1); STW(br, brg, 1);
    LDS_FENCE;
    STORE(right);
    __syncthreads();           // (4) wp staging done; SB -> og layout [128][132]

    // ---- og: GEMM (V only), block stage, coalesced int4 stores ----
    const u16* WO = Wt + (size_t)4 * 16384;
#pragma unroll 1
    for (int cf = 0; cf < 2; ++cf){
        const int col = nb + cf * 16 + lrow;
#pragma unroll
        for (int rf = 0; rf < 4; ++rf) aV[rf] = zero4;
#pragma unroll
        for (int ks = 0; ks < 4; ++ks){
            bf16x8 bv = *reinterpret_cast<const bf16x8*>(WO + (size_t)col * 128 + ks * 32 + g * 8);
#pragma unroll
            for (int rf = 0; rf < 4; ++rf)
                aV[rf] = __builtin_amdgcn_mfma_f32_16x16x32_bf16(af[ks][rf], bv, aV[rf], 0, 0, 0);
        }
        const float bOv = bog[col];
#pragma unroll
        for (int rf = 0; rf < 4; ++rf)
#pragma unroll
            for (int j = 0; j < 4; ++j){
                const int lr = h * 64 + rf * 16 + orow + j;
                SB[lr * 132 + col] = f2bf(sigmoidf_(aV[rf][j] + bOv));
            }
    }
    __syncthreads();           // (5) og staging ready
    {
        const int lr = t >> 2, c4 = (t & 3) * 32;
        const size_t gb = ((size_t)(a0 + (lr & 15)) * Ns + b0 + (lr >> 4)) * Cc + c4;
#pragma unroll
        for (int s = 0; s < 4; ++s){
            int4 v = *reinterpret_cast<const int4*>(&SB[lr * 132 + c4 + s * 8]);
            *reinterpret_cast<int4*>(og + gb + s * 8) = v;
        }
    }
}

// ---------------------------------------------------------------------------
// K2: om[c][i][j] = sum_k left[c][k][i] * right[c][k][j]   (per-channel GEMM)
// 1-D grid 2048, XCD-swizzled so each XCD owns 16 whole channels.
// ---------------------------------------------------------------------------
#define K2_LOAD(AF, BF, KS) do {                                                    \
    const size_t kbrow_ = (size_t)((KS) * 4 + lkb) * Ns;                            \
    _Pragma("unroll") for (int rf = 0; rf < 4; ++rf)                                \
        AF[rf] = *reinterpret_cast<const bf16x8*>(Lc + (kbrow_ + ib + rf * 16 + lrow) * 8); \
    _Pragma("unroll") for (int cf = 0; cf < 4; ++cf)                                \
        BF[cf] = *reinterpret_cast<const bf16x8*>(Rc + (kbrow_ + jb + cf * 16 + lrow) * 8); \
} while (0)

#define K2_MM(AF, BF) do {                                                          \
    _Pragma("unroll") for (int rf = 0; rf < 4; ++rf)                                \
    _Pragma("unroll") for (int cf = 0; cf < 4; ++cf)                                \
        acc[rf][cf] = __builtin_amdgcn_mfma_f32_16x16x32_bf16(AF[rf], BF[cf], acc[rf][cf], 0, 0, 0); \
} while (0)

__global__ __launch_bounds__(256) void k2(const u16* __restrict__ left,
                                          const u16* __restrict__ right,
                                          u16* __restrict__ om)
{
    __shared__ u16 sO[128][136];
    const int bid = blockIdx.x;
    const int xcd = bid & 7, idxx = bid >> 3;
    const int virt = xcd * 256 + idxx;
    const int c    = virt >> 4;
    const int tile = virt & 15;
    const int iy = tile >> 2, jx = tile & 3;
    const int t = threadIdx.x, w = t >> 6, l = t & 63;
    const int wr = w >> 1, wc = w & 1;
    const int ib = iy * 128 + wr * 64;
    const int jb = jx * 128 + wc * 64;
    const int lrow = l & 15, lkb = l >> 4;
    const u16* Lc = left  + (size_t)c * (Ns * Ns);
    const u16* Rc = right + (size_t)c * (Ns * Ns);
    const f32x4 zero4 = {0.f, 0.f, 0.f, 0.f};
    f32x4 acc[4][4];
#pragma unroll
    for (int rf = 0; rf < 4; ++rf)
#pragma unroll
        for (int cf = 0; cf < 4; ++cf) acc[rf][cf] = zero4;

    bf16x8 a0f[4], b0f[4], a1f[4], b1f[4];
    K2_LOAD(a0f, b0f, 0);
#pragma unroll
    for (int ks = 0; ks < 16; ks += 2){
        K2_LOAD(a1f, b1f, ks + 1);
        K2_MM(a0f, b0f);
        if (ks + 2 < 16) K2_LOAD(a0f, b0f, ks + 2);
        K2_MM(a1f, b1f);
    }

    const int orow = (l >> 4) << 2;
#pragma unroll
    for (int rf = 0; rf < 4; ++rf)
#pragma unroll
        for (int j2 = 0; j2 < 4; ++j2){
            const int rloc = wr * 64 + rf * 16 + orow + j2;
#pragma unroll
            for (int cf = 0; cf < 4; ++cf)
                sO[rloc][wc * 64 + cf * 16 + lrow] = f2bf(acc[rf][cf][j2]);
        }
    __syncthreads();
    u16* obase = om + (size_t)c * Ns * Ns + (size_t)(iy * 128) * Ns + jx * 128;
#pragma unroll
    for (int s = 0; s < 8; ++s){
        const int gg = s * 256 + t;
        const int row = gg >> 4, co = (gg & 15) * 8;
        int4 v = *reinterpret_cast<const int4*>(&sO[row][co]);
        *reinterpret_cast<int4*>(obase + (size_t)row * Ns + co) = v;
    }
}

// ---------------------------------------------------------------------------
// K3: final = sigmoid(og) * (LN_c(out_mid) @ Wo + bo), fp32 out [i][j][c]
// ---------------------------------------------------------------------------
__global__ __launch_bounds__(256) void k3(
    const u16* __restrict__ om, const u16* __restrict__ og, const u16* __restrict__ Wt,
    const float* __restrict__ g2, const float* __restrict__ b2, const float* __restrict__ bo,
    float* __restrict__ out)
{
    __shared__ char smem[34816];
    u16* X = reinterpret_cast<u16*>(smem);
    u16* O = reinterpret_cast<u16*>(smem) + 8704;
    __shared__ float sg2[128], sb2[128];
    const int i  = blockIdx.y;
    const int j0 = blockIdx.x * 64;
    const int t  = threadIdx.x;
    if (t < 128){ sg2[t] = g2[t]; sb2[t] = b2[t]; }
    {
        const int c = t >> 1, jh = (t & 1) * 32;
        const u16* src = om + (size_t)c * Ns * Ns + (size_t)i * Ns + j0 + jh;
#pragma unroll
        for (int s = 0; s < 8; ++s){
            ushort4 v = reinterpret_cast<const ushort4*>(src)[s];
            const int jj = jh + s * 4;
            X[(jj + 0) * 136 + c] = v.x; X[(jj + 1) * 136 + c] = v.y;
            X[(jj + 2) * 136 + c] = v.z; X[(jj + 3) * 136 + c] = v.w;
        }
    }
    {
        const int jj = t >> 2, qq = t & 3;
        const u16* src = og + ((size_t)i * Ns + j0 + jj) * Cc + qq * 32;
#pragma unroll
        for (int s = 0; s < 4; ++s)
            *reinterpret_cast<int4*>(&O[jj * 136 + qq * 32 + s * 8]) = reinterpret_cast<const int4*>(src)[s];
    }
    __syncthreads();
    const int r = t >> 2, q = t & 3;
    {
        float s1 = 0.f, s2v = 0.f;
#pragma unroll
        for (int e = 0; e < 32; ++e){
            const float v = bf2f(X[r * 136 + q * 32 + e]);
            s1 += v; s2v += v * v;
        }
        s1  += __shfl_xor(s1, 1);  s1  += __shfl_xor(s1, 2);
        s2v += __shfl_xor(s2v, 1); s2v += __shfl_xor(s2v, 2);
        const float mm  = s1 * (1.0f / 128.0f);
        const float rsv = rsqrtf(s2v * (1.0f / 128.0f) - mm * mm + EPSV);
#pragma unroll
        for (int e = 0; e < 32; ++e){
            const int cc = q * 32 + e;
            const float v = bf2f(X[r * 136 + cc]);
            X[r * 136 + cc] = f2bf((v - mm) * rsv * sg2[cc] + sb2[cc]);
        }
    }
    __syncthreads();
    const int w = t >> 6, l = t & 63;
    const int lrow = l & 15, lk = (l >> 4) << 3, nbv = w * 32, orow = (l >> 4) << 2;
    const u16* WO = Wt + (size_t)5 * 16384;
    const f32x4 zero4 = {0.f, 0.f, 0.f, 0.f};
    f32x4 acc[4][2];
#pragma unroll
    for (int rf = 0; rf < 4; ++rf)
#pragma unroll
        for (int cf = 0; cf < 2; ++cf) acc[rf][cf] = zero4;
#pragma unroll
    for (int ks = 0; ks < 4; ++ks){
        const int k0 = ks * 32 + lk;
        bf16x8 af[4];
#pragma unroll
        for (int rf = 0; rf < 4; ++rf)
            af[rf] = *reinterpret_cast<const bf16x8*>(&X[(rf * 16 + lrow) * 136 + k0]);
#pragma unroll
        for (int cf = 0; cf < 2; ++cf){
            bf16x8 bv = *reinterpret_cast<const bf16x8*>(WO + (size_t)(nbv + cf * 16 + lrow) * 128 + k0);
#pragma unroll
            for (int rf = 0; rf < 4; ++rf)
                acc[rf][cf] = __builtin_amdgcn_mfma_f32_16x16x32_bf16(af[rf], bv, acc[rf][cf], 0, 0, 0);
        }
    }
    float gv[2][4][4];
#pragma unroll
    for (int cf = 0; cf < 2; ++cf){
        const int cg = nbv + cf * 16 + lrow;
        const float bov = bo[cg];
#pragma unroll
        for (int rf = 0; rf < 4; ++rf)
#pragma unroll
            for (int j = 0; j < 4; ++j){
                const int row = rf * 16 + orow + j;
                gv[cf][rf][j] = bf2f(O[row * 136 + cg]) * (acc[rf][cf][j] + bov);
            }
    }
    __syncthreads();
    float* sF = reinterpret_cast<float*>(smem);
#pragma unroll
    for (int cf = 0; cf < 2; ++cf){
        const int cg = nbv + cf * 16 + lrow;
#pragma unroll
        for (int rf = 0; rf < 4; ++rf)
#pragma unroll
            for (int j = 0; j < 4; ++j){
                const int row = rf * 16 + orow + j;
                sF[row * 128 + cg] = gv[cf][rf][j];
            }
    }
    __syncthreads();
    const float4* sF4 = reinterpret_cast<const float4*>(smem);
    float* obase = out + ((size_t)i * Ns + j0) * Cc;
#pragma unroll
    for (int s = 0; s < 8; ++s){
        const int gg = s * 256 + t;
        const int row = gg >> 5, co = (gg & 31) * 4;
        float4 v = sF4[gg];
        *reinterpret_cast<float4*>(obase + (size_t)row * Cc + co) = v;
    }
}

// ---------------------------------------------------------------------------
extern "C" void kernel_launch(void* const* d_in, const int* in_sizes, int n_in,
                              void* d_out, int out_size, void* d_ws, size_t ws_size,
                              hipStream_t stream)
{
    const float* x    = (const float*)d_in[0];
    const float* ling = (const float*)d_in[1];
    const float* linb = (const float*)d_in[2];
    const float* loutg= (const float*)d_in[3];
    const float* loutb= (const float*)d_in[4];
    const float* Wl   = (const float*)d_in[5];
    const float* bl   = (const float*)d_in[6];
    const float* Wr   = (const float*)d_in[7];
    const float* br   = (const float*)d_in[8];
    const float* Wo   = (const float*)d_in[9];
    const float* bo   = (const float*)d_in[10];
    const float* Wlg  = (const float*)d_in[11];
    const float* blg  = (const float*)d_in[12];
    const float* Wrg  = (const float*)d_in[13];
    const float* brg  = (const float*)d_in[14];
    const float* Wog  = (const float*)d_in[15];
    const float* bog  = (const float*)d_in[16];

    char* ws = (char*)d_ws;
    u16* Wt = (u16*)ws;
    const size_t off = 256 * 1024;
    const size_t SZ  = (size_t)33554432 * 2;   // 64 MiB per bf16 tensor
    u16* left  = (u16*)(ws + off);
    u16* right = (u16*)(ws + off + SZ);
    u16* og    = (u16*)(ws + off + 2 * SZ);
    u16* om    = (u16*)(ws + off + 3 * SZ);

    hipLaunchKernelGGL(k_prep, dim3(384), dim3(256), 0, stream, Wl, Wlg, Wr, Wrg, Wog, Wo, Wt);
    hipLaunchKernelGGL(k1, dim3(2048), dim3(512), 0, stream,
                       x, ling, linb, Wt, bl, blg, br, brg, bog, left, right, og);
    hipLaunchKernelGGL(k2, dim3(2048), dim3(256), 0, stream, left, right, om);
    hipLaunchKernelGGL(k3, dim3(8, 512), dim3(256), 0, stream, om, og, Wt, loutg, loutb, bo, (float*)d_out);
}

// Round 11
// 266.690 us; speedup vs baseline: 1.0806x; 1.0806x over previous
//
#include <hip/hip_runtime.h>
#include <hip/hip_bf16.h>
#include <cstdint>
#include <cstddef>

typedef unsigned short u16;
typedef short bf16x8 __attribute__((ext_vector_type(8)));
typedef float f32x4 __attribute__((ext_vector_type(4)));

constexpr int Ns = 512;   // N
constexpr int Dd = 128;   // D
constexpr int Cc = 128;   // C
#define EPSV 1e-5f

__device__ __forceinline__ u16 f2bf(float f){
    __hip_bfloat16 h = __float2bfloat16(f);
    return *reinterpret_cast<u16*>(&h);
}
__device__ __forceinline__ float bf2f(u16 h){
    return __uint_as_float(((uint32_t)h) << 16);
}
__device__ __forceinline__ float sigmoidf_(float x){
    return __builtin_amdgcn_rcpf(1.0f + __expf(-x));   // ~1ulp, fine at bf16
}

// same-wave LDS write->read ordering fence (guide rule #18)
#define LDS_FENCE do {                                         \
    asm volatile("s_waitcnt lgkmcnt(0)" ::: "memory");         \
    __builtin_amdgcn_sched_barrier(0);                         \
} while (0)

// ---------------------------------------------------------------------------
// K0: weights -> bf16, transposed [n][k].  Order: Wl,Wlg,Wr,Wrg,Wog,Wo
// ---------------------------------------------------------------------------
__global__ void k_prep(const float* __restrict__ Wl, const float* __restrict__ Wlg,
                       const float* __restrict__ Wr, const float* __restrict__ Wrg,
                       const float* __restrict__ Wog, const float* __restrict__ Wo,
                       u16* __restrict__ Wt){
    int idx = blockIdx.x * 256 + threadIdx.x;
    if (idx >= 6 * 16384) return;
    int m = idx >> 14; int nk = idx & 16383; int n = nk >> 7; int k = nk & 127;
    const float* W = (m == 0) ? Wl : (m == 1) ? Wlg : (m == 2) ? Wr
                   : (m == 3) ? Wrg : (m == 4) ? Wog : Wo;
    Wt[idx] = f2bf(W[k * Cc + n]);
}

// ---------------------------------------------------------------------------
// K1: LN(x) then 4 GEMMs (Wl,Wlg -> left; Wr,Wrg -> right).  R9-verified
// structure; og phase REMOVED (now fused into k3) -> 1/3 less GEMM work,
// writes 201 -> 134 MB, 2 fewer barriers.
// ---------------------------------------------------------------------------
__global__ __launch_bounds__(256) void k1(
    const float* __restrict__ x, const float* __restrict__ g_ln, const float* __restrict__ b_ln,
    const u16* __restrict__ Wt,
    const float* __restrict__ bl, const float* __restrict__ blg,
    const float* __restrict__ br, const float* __restrict__ brg,
    u16* __restrict__ left, u16* __restrict__ right)
{
    __shared__ u16  SB[8704];          // aliased: xn [64][136] / wp-stage [4][32][68]
    __shared__ float gln[128], bln[128];

    const int t   = threadIdx.x;
    const int bid = blockIdx.x;
    const int a0  = (bid >> 6) << 3;
    const int b0  = (bid & 63) << 3;
    const int w = t >> 6, l = t & 63;
    const int lrow = l & 15, g = l >> 4;
    const int nb = w * 32;
    const int orow = g << 2;
    const int kb = a0 >> 3;

    // ---- prologue: x loads, LN stats, normalize into SB-as-xn ----
    const int r = t >> 2, q = t & 3;
    const int aa = a0 + (r & 7), bb = b0 + (r >> 3);
    const float4* xrow = reinterpret_cast<const float4*>(x + ((size_t)aa * Ns + bb) * Dd);
    float4 xv[8];
#pragma unroll
    for (int i2 = 0; i2 < 8; ++i2) xv[i2] = xrow[q + 4 * i2];
    if (t < 128){ gln[t] = g_ln[t]; bln[t] = b_ln[t]; }

    float s1 = 0.f, s2 = 0.f;
#pragma unroll
    for (int i2 = 0; i2 < 8; ++i2){
        float4 v = xv[i2];
        s1 += v.x + v.y + v.z + v.w;
        s2 += v.x * v.x + v.y * v.y + v.z * v.z + v.w * v.w;
    }
    s1 += __shfl_xor(s1, 1); s1 += __shfl_xor(s1, 2);
    s2 += __shfl_xor(s2, 1); s2 += __shfl_xor(s2, 2);
    const float mm  = s1 * (1.0f / 128.0f);
    const float rsv = rsqrtf(s2 * (1.0f / 128.0f) - mm * mm + EPSV);
    __syncthreads();                   // (1) gln/bln ready
#pragma unroll
    for (int i2 = 0; i2 < 8; ++i2){
        const int d = (q + 4 * i2) * 4;
        ushort4 o;
        o.x = f2bf((xv[i2].x - mm) * rsv * gln[d + 0] + bln[d + 0]);
        o.y = f2bf((xv[i2].y - mm) * rsv * gln[d + 1] + bln[d + 1]);
        o.z = f2bf((xv[i2].z - mm) * rsv * gln[d + 2] + bln[d + 2]);
        o.w = f2bf((xv[i2].w - mm) * rsv * gln[d + 3] + bln[d + 3]);
        *reinterpret_cast<ushort4*>(&SB[r * 136 + d]) = o;
    }
    __syncthreads();                   // (2) xn ready

    // ---- A-fragments once (R4-verified) ----
    bf16x8 af[4][4];
#pragma unroll
    for (int ks = 0; ks < 4; ++ks)
#pragma unroll
        for (int rf = 0; rf < 4; ++rf)
            af[ks][rf] = *reinterpret_cast<const bf16x8*>(&SB[(rf * 16 + lrow) * 136 + ks * 32 + g * 8]);
    __syncthreads();                   // (3) all af reads done; SB free

    u16* SBw = &SB[w * 32 * 68];       // wave-private staging (32 cols x 68)
    const f32x4 zero4 = {0.f, 0.f, 0.f, 0.f};
    f32x4 aV[4], aG[4];

    auto GEMM1 = [&](const u16* WV, const u16* WG, int cf){
        const int col = nb + cf * 16 + lrow;
#pragma unroll
        for (int rf = 0; rf < 4; ++rf){ aV[rf] = zero4; aG[rf] = zero4; }
#pragma unroll
        for (int ks = 0; ks < 4; ++ks){
            bf16x8 bv = *reinterpret_cast<const bf16x8*>(WV + (size_t)col * 128 + ks * 32 + g * 8);
            bf16x8 bg = *reinterpret_cast<const bf16x8*>(WG + (size_t)col * 128 + ks * 32 + g * 8);
#pragma unroll
            for (int rf = 0; rf < 4; ++rf)
                aV[rf] = __builtin_amdgcn_mfma_f32_16x16x32_bf16(af[ks][rf], bv, aV[rf], 0, 0, 0);
#pragma unroll
            for (int rf = 0; rf < 4; ++rf)
                aG[rf] = __builtin_amdgcn_mfma_f32_16x16x32_bf16(af[ks][rf], bg, aG[rf], 0, 0, 0);
        }
    };
    auto STW = [&](const float* bV, const float* bG, int cf){
        const int cl2 = cf * 16 + lrow;
        const int col = nb + cl2;
        const float bVv = bV[col], bGv = bG[col];
#pragma unroll
        for (int rf = 0; rf < 4; ++rf){
            ushort4 pk;
#pragma unroll
            for (int j = 0; j < 4; ++j){
                const float vv = aV[rf][j] + bVv;
                const float gg = aG[rf][j] + bGv;
                ((u16*)&pk)[j] = f2bf(sigmoidf_(gg) * vv);
            }
            *reinterpret_cast<ushort4*>(&SBw[cl2 * 68 + rf * 16 + orow]) = pk;
        }
    };
    auto STORE = [&](u16* dst){
#pragma unroll
        for (int it = 0; it < 4; ++it){
            const int cl2 = it * 8 + (l >> 3);
            const int s   = l & 7;
            int4 v = *reinterpret_cast<const int4*>(&SBw[cl2 * 68 + s * 8]);
            *reinterpret_cast<int4*>(dst + (((size_t)(nb + cl2) * 64 + kb) * Ns + b0) * 8 + s * 8) = v;
        }
    };

    // ---- barrier-free L/R pipeline (per-wave; fences order same-wave LDS reuse) ----
    GEMM1(Wt,             Wt + 16384,     0); STW(bl, blg, 0);
    GEMM1(Wt,             Wt + 16384,     1); STW(bl, blg, 1);
    LDS_FENCE;
    STORE(left);
    LDS_FENCE;
    GEMM1(Wt + 2 * 16384, Wt + 3 * 16384, 0); STW(br, brg, 0);
    GEMM1(Wt + 2 * 16384, Wt + 3 * 16384, 1); STW(br, brg, 1);
    LDS_FENCE;
    STORE(right);
}

// ---------------------------------------------------------------------------
// K2: om[c][i][j] = sum_k left[c][k][i] * right[c][k][j]   (per-channel GEMM)
// 1-D grid 2048, XCD-swizzled so each XCD owns 16 whole channels.  (frozen)
// ---------------------------------------------------------------------------
#define K2_LOAD(AF, BF, KS) do {                                                    \
    const size_t kbrow_ = (size_t)((KS) * 4 + lkb) * Ns;                            \
    _Pragma("unroll") for (int rf = 0; rf < 4; ++rf)                                \
        AF[rf] = *reinterpret_cast<const bf16x8*>(Lc + (kbrow_ + ib + rf * 16 + lrow) * 8); \
    _Pragma("unroll") for (int cf = 0; cf < 4; ++cf)                                \
        BF[cf] = *reinterpret_cast<const bf16x8*>(Rc + (kbrow_ + jb + cf * 16 + lrow) * 8); \
} while (0)

#define K2_MM(AF, BF) do {                                                          \
    _Pragma("unroll") for (int rf = 0; rf < 4; ++rf)                                \
    _Pragma("unroll") for (int cf = 0; cf < 4; ++cf)                                \
        acc[rf][cf] = __builtin_amdgcn_mfma_f32_16x16x32_bf16(AF[rf], BF[cf], acc[rf][cf], 0, 0, 0); \
} while (0)

__global__ __launch_bounds__(256) void k2(const u16* __restrict__ left,
                                          const u16* __restrict__ right,
                                          u16* __restrict__ om)
{
    __shared__ u16 sO[128][136];
    const int bid = blockIdx.x;
    const int xcd = bid & 7, idxx = bid >> 3;
    const int virt = xcd * 256 + idxx;
    const int c    = virt >> 4;
    const int tile = virt & 15;
    const int iy = tile >> 2, jx = tile & 3;
    const int t = threadIdx.x, w = t >> 6, l = t & 63;
    const int wr = w >> 1, wc = w & 1;
    const int ib = iy * 128 + wr * 64;
    const int jb = jx * 128 + wc * 64;
    const int lrow = l & 15, lkb = l >> 4;
    const u16* Lc = left  + (size_t)c * (Ns * Ns);
    const u16* Rc = right + (size_t)c * (Ns * Ns);
    const f32x4 zero4 = {0.f, 0.f, 0.f, 0.f};
    f32x4 acc[4][4];
#pragma unroll
    for (int rf = 0; rf < 4; ++rf)
#pragma unroll
        for (int cf = 0; cf < 4; ++cf) acc[rf][cf] = zero4;

    bf16x8 a0f[4], b0f[4], a1f[4], b1f[4];
    K2_LOAD(a0f, b0f, 0);
#pragma unroll
    for (int ks = 0; ks < 16; ks += 2){
        K2_LOAD(a1f, b1f, ks + 1);
        K2_MM(a0f, b0f);
        if (ks + 2 < 16) K2_LOAD(a0f, b0f, ks + 2);
        K2_MM(a1f, b1f);
    }

    const int orow = (l >> 4) << 2;
#pragma unroll
    for (int rf = 0; rf < 4; ++rf)
#pragma unroll
        for (int j2 = 0; j2 < 4; ++j2){
            const int rloc = wr * 64 + rf * 16 + orow + j2;
#pragma unroll
            for (int cf = 0; cf < 4; ++cf)
                sO[rloc][wc * 64 + cf * 16 + lrow] = f2bf(acc[rf][cf][j2]);
        }
    __syncthreads();
    u16* obase = om + (size_t)c * Ns * Ns + (size_t)(iy * 128) * Ns + jx * 128;
#pragma unroll
    for (int s = 0; s < 8; ++s){
        const int gg = s * 256 + t;
        const int row = gg >> 4, co = (gg & 15) * 8;
        int4 v = *reinterpret_cast<const int4*>(&sO[row][co]);
        *reinterpret_cast<int4*>(obase + (size_t)row * Ns + co) = v;
    }
}

// ---------------------------------------------------------------------------
// K3: out = sigmoid(LN_in(x) @ Wog + bog) * (LN_c(om) @ Wo + bo), fp32 out.
// og is computed HERE (fused from k1): x row load (coalesced 32KB/block),
// LN_in via 4-lane shuffle, dual GEMM from two LDS A-buffers.
// ---------------------------------------------------------------------------
__global__ __launch_bounds__(256) void k3(
    const u16* __restrict__ om, const float* __restrict__ x,
    const float* __restrict__ g1, const float* __restrict__ b1,
    const u16* __restrict__ Wt,
    const float* __restrict__ g2, const float* __restrict__ b2,
    const float* __restrict__ bogv, const float* __restrict__ bo,
    float* __restrict__ out)
{
    __shared__ char smem[34816];
    u16* X  = reinterpret_cast<u16*>(smem);           // [64][136] om tile -> LN_c
    u16* Xn = reinterpret_cast<u16*>(smem) + 8704;    // [64][136] xn = LN_in(x)
    __shared__ float sg2[128], sb2[128], sg1[128], sb1[128];
    const int i  = blockIdx.y;
    const int j0 = blockIdx.x * 64;
    const int t  = threadIdx.x;
    if (t < 128){ sg2[t] = g2[t]; sb2[t] = b2[t]; sg1[t] = g1[t]; sb1[t] = b1[t]; }

    const int r = t >> 2, q = t & 3;      // 4 threads per j-row
    // ---- x row loads + LN_in stats (shuffle) ----
    const float4* xr = reinterpret_cast<const float4*>(x + ((size_t)i * Ns + j0 + r) * Dd);
    float4 xv[8];
#pragma unroll
    for (int i2 = 0; i2 < 8; ++i2) xv[i2] = xr[q + 4 * i2];
    float s1 = 0.f, s2 = 0.f;
#pragma unroll
    for (int i2 = 0; i2 < 8; ++i2){
        float4 v = xv[i2];
        s1 += v.x + v.y + v.z + v.w;
        s2 += v.x * v.x + v.y * v.y + v.z * v.z + v.w * v.w;
    }
    s1 += __shfl_xor(s1, 1); s1 += __shfl_xor(s1, 2);
    s2 += __shfl_xor(s2, 1); s2 += __shfl_xor(s2, 2);
    const float mm1  = s1 * (1.0f / 128.0f);
    const float rsv1 = rsqrtf(s2 * (1.0f / 128.0f) - mm1 * mm1 + EPSV);

    // ---- om transpose load into X ([c][j] -> [j][c]) ----
    {
        const int c = t >> 1, jh = (t & 1) * 32;
        const u16* src = om + (size_t)c * Ns * Ns + (size_t)i * Ns + j0 + jh;
#pragma unroll
        for (int s = 0; s < 8; ++s){
            ushort4 v = reinterpret_cast<const ushort4*>(src)[s];
            const int jj = jh + s * 4;
            X[(jj + 0) * 136 + c] = v.x; X[(jj + 1) * 136 + c] = v.y;
            X[(jj + 2) * 136 + c] = v.z; X[(jj + 3) * 136 + c] = v.w;
        }
    }
    __syncthreads();                      // (1) params ready
    // ---- normalize x -> Xn ----
#pragma unroll
    for (int i2 = 0; i2 < 8; ++i2){
        const int d = (q + 4 * i2) * 4;
        ushort4 o;
        o.x = f2bf((xv[i2].x - mm1) * rsv1 * sg1[d + 0] + sb1[d + 0]);
        o.y = f2bf((xv[i2].y - mm1) * rsv1 * sg1[d + 1] + sb1[d + 1]);
        o.z = f2bf((xv[i2].z - mm1) * rsv1 * sg1[d + 2] + sb1[d + 2]);
        o.w = f2bf((xv[i2].w - mm1) * rsv1 * sg1[d + 3] + sb1[d + 3]);
        *reinterpret_cast<ushort4*>(&Xn[r * 136 + d]) = o;
    }
    __syncthreads();                      // (2) X raw + Xn complete
    // ---- LN over c on X (in place; 4 lanes own each row) ----
    {
        float a1 = 0.f, a2 = 0.f;
#pragma unroll
        for (int e = 0; e < 32; ++e){
            const float v = bf2f(X[r * 136 + q * 32 + e]);
            a1 += v; a2 += v * v;
        }
        a1 += __shfl_xor(a1, 1); a1 += __shfl_xor(a1, 2);
        a2 += __shfl_xor(a2, 1); a2 += __shfl_xor(a2, 2);
        const float mm  = a1 * (1.0f / 128.0f);
        const float rsv = rsqrtf(a2 * (1.0f / 128.0f) - mm * mm + EPSV);
#pragma unroll
        for (int e = 0; e < 32; ++e){
            const int cc = q * 32 + e;
            const float v = bf2f(X[r * 136 + cc]);
            X[r * 136 + cc] = f2bf((v - mm) * rsv * sg2[cc] + sb2[cc]);
        }
    }
    __syncthreads();                      // (3) GEMM inputs ready

    // ---- dual GEMM: accW = X @ WoT, accO = Xn @ WogT ----
    const int w = t >> 6, l = t & 63;
    const int lrow = l & 15, lk = (l >> 4) << 3, nbv = w * 32, orow = (l >> 4) << 2;
    const u16* WOG = Wt + (size_t)4 * 16384;
    const u16* WO  = Wt + (size_t)5 * 16384;
    const f32x4 zero4 = {0.f, 0.f, 0.f, 0.f};
    f32x4 accW[4][2], accO[4][2];
#pragma unroll
    for (int rf = 0; rf < 4; ++rf)
#pragma unroll
        for (int cf = 0; cf < 2; ++cf){ accW[rf][cf] = zero4; accO[rf][cf] = zero4; }
#pragma unroll
    for (int ks = 0; ks < 4; ++ks){
        const int k0 = ks * 32 + lk;
        bf16x8 af[4], afn[4];
#pragma unroll
        for (int rf = 0; rf < 4; ++rf){
            af[rf]  = *reinterpret_cast<const bf16x8*>(&X[(rf * 16 + lrow) * 136 + k0]);
            afn[rf] = *reinterpret_cast<const bf16x8*>(&Xn[(rf * 16 + lrow) * 136 + k0]);
        }
#pragma unroll
        for (int cf = 0; cf < 2; ++cf){
            const int colg = nbv + cf * 16 + lrow;
            bf16x8 bv = *reinterpret_cast<const bf16x8*>(WO  + (size_t)colg * 128 + k0);
            bf16x8 bg = *reinterpret_cast<const bf16x8*>(WOG + (size_t)colg * 128 + k0);
#pragma unroll
            for (int rf = 0; rf < 4; ++rf)
                accW[rf][cf] = __builtin_amdgcn_mfma_f32_16x16x32_bf16(af[rf], bv, accW[rf][cf], 0, 0, 0);
#pragma unroll
            for (int rf = 0; rf < 4; ++rf)
                accO[rf][cf] = __builtin_amdgcn_mfma_f32_16x16x32_bf16(afn[rf], bg, accO[rf][cf], 0, 0, 0);
        }
    }
    // ---- gate in registers ----
    float gv[2][4][4];
#pragma unroll
    for (int cf = 0; cf < 2; ++cf){
        const int cg = nbv + cf * 16 + lrow;
        const float bov = bo[cg], bogc = bogv[cg];
#pragma unroll
        for (int rf = 0; rf < 4; ++rf)
#pragma unroll
            for (int j = 0; j < 4; ++j)
                gv[cf][rf][j] = sigmoidf_(accO[rf][cf][j] + bogc) * (accW[rf][cf][j] + bov);
    }
    __syncthreads();                      // (4) X/Xn reads done; smem -> sF
    float* sF = reinterpret_cast<float*>(smem);
#pragma unroll
    for (int cf = 0; cf < 2; ++cf){
        const int cg = nbv + cf * 16 + lrow;
#pragma unroll
        for (int rf = 0; rf < 4; ++rf)
#pragma unroll
            for (int j = 0; j < 4; ++j){
                const int row = rf * 16 + orow + j;
                sF[row * 128 + cg] = gv[cf][rf][j];
            }
    }
    __syncthreads();                      // (5) sF ready
    const float4* sF4 = reinterpret_cast<const float4*>(smem);
    float* obase = out + ((size_t)i * Ns + j0) * Cc;
#pragma unroll
    for (int s = 0; s < 8; ++s){
        const int gg = s * 256 + t;
        const int row = gg >> 5, co = (gg & 31) * 4;
        float4 v = sF4[gg];
        *reinterpret_cast<float4*>(obase + (size_t)row * Cc + co) = v;
    }
}

// ---------------------------------------------------------------------------
extern "C" void kernel_launch(void* const* d_in, const int* in_sizes, int n_in,
                              void* d_out, int out_size, void* d_ws, size_t ws_size,
                              hipStream_t stream)
{
    const float* x    = (const float*)d_in[0];
    const float* ling = (const float*)d_in[1];
    const float* linb = (const float*)d_in[2];
    const float* loutg= (const float*)d_in[3];
    const float* loutb= (const float*)d_in[4];
    const float* Wl   = (const float*)d_in[5];
    const float* bl   = (const float*)d_in[6];
    const float* Wr   = (const float*)d_in[7];
    const float* br   = (const float*)d_in[8];
    const float* Wo   = (const float*)d_in[9];
    const float* bo   = (const float*)d_in[10];
    const float* Wlg  = (const float*)d_in[11];
    const float* blg  = (const float*)d_in[12];
    const float* Wrg  = (const float*)d_in[13];
    const float* brg  = (const float*)d_in[14];
    const float* Wog  = (const float*)d_in[15];
    const float* bog  = (const float*)d_in[16];

    char* ws = (char*)d_ws;
    u16* Wt = (u16*)ws;
    const size_t off = 256 * 1024;
    const size_t SZ  = (size_t)33554432 * 2;   // 64 MiB per bf16 tensor
    u16* left  = (u16*)(ws + off);
    u16* right = (u16*)(ws + off + SZ);
    u16* om    = (u16*)(ws + off + 2 * SZ);

    hipLaunchKernelGGL(k_prep, dim3(384), dim3(256), 0, stream, Wl, Wlg, Wr, Wrg, Wog, Wo, Wt);
    hipLaunchKernelGGL(k1, dim3(4096), dim3(256), 0, stream,
                       x, ling, linb, Wt, bl, blg, br, brg, left, right);
    hipLaunchKernelGGL(k2, dim3(2048), dim3(256), 0, stream, left, right, om);
    hipLaunchKernelGGL(k3, dim3(8, 512), dim3(256), 0, stream,
                       om, x, ling, linb, Wt, loutg, loutb, bog, bo, (float*)d_out);
}

// Round 12
// 259.379 us; speedup vs baseline: 1.1111x; 1.0282x over previous
//
#include <hip/hip_runtime.h>
#include <hip/hip_bf16.h>
#include <cstdint>
#include <cstddef>

typedef unsigned short u16;
typedef short bf16x8 __attribute__((ext_vector_type(8)));
typedef float f32x4 __attribute__((ext_vector_type(4)));

constexpr int Ns = 512;   // N
constexpr int Dd = 128;   // D
constexpr int Cc = 128;   // C
#define EPSV 1e-5f

__device__ __forceinline__ u16 f2bf(float f){
    __hip_bfloat16 h = __float2bfloat16(f);
    return *reinterpret_cast<u16*>(&h);
}
__device__ __forceinline__ float bf2f(u16 h){
    return __uint_as_float(((uint32_t)h) << 16);
}
__device__ __forceinline__ float sigmoidf_(float x){
    return __builtin_amdgcn_rcpf(1.0f + __expf(-x));   // ~1ulp, fine at bf16
}

// same-wave LDS write->read ordering fence (guide rule #18)
#define LDS_FENCE do {                                         \
    asm volatile("s_waitcnt lgkmcnt(0)" ::: "memory");         \
    __builtin_amdgcn_sched_barrier(0);                         \
} while (0)

// ---------------------------------------------------------------------------
// K0: weights -> bf16, transposed [n][k].  Order: Wl,Wlg,Wr,Wrg,Wog,Wo
// ---------------------------------------------------------------------------
__global__ void k_prep(const float* __restrict__ Wl, const float* __restrict__ Wlg,
                       const float* __restrict__ Wr, const float* __restrict__ Wrg,
                       const float* __restrict__ Wog, const float* __restrict__ Wo,
                       u16* __restrict__ Wt){
    int idx = blockIdx.x * 256 + threadIdx.x;
    if (idx >= 6 * 16384) return;
    int m = idx >> 14; int nk = idx & 16383; int n = nk >> 7; int k = nk & 127;
    const float* W = (m == 0) ? Wl : (m == 1) ? Wlg : (m == 2) ? Wr
                   : (m == 3) ? Wrg : (m == 4) ? Wog : Wo;
    Wt[idx] = f2bf(W[k * Cc + n]);
}

// ---------------------------------------------------------------------------
// K1: LN(x), then L/R pairs (R11-verified, wave-private) + og phase with
// wave-private staging (stride 36, b64 readback) — NO og block barriers.
// SB partition: per-wave region w*2304 holds BOTH the L/R stage (stride 68,
// 2176 used) and later the og stage (stride 36, 2304 used); same-wave reuse
// ordered by LDS_FENCE.
// ---------------------------------------------------------------------------
__global__ __launch_bounds__(256) void k1(
    const float* __restrict__ x, const float* __restrict__ g_ln, const float* __restrict__ b_ln,
    const u16* __restrict__ Wt,
    const float* __restrict__ bl, const float* __restrict__ blg,
    const float* __restrict__ br, const float* __restrict__ brg,
    const float* __restrict__ bog,
    u16* __restrict__ left, u16* __restrict__ right, u16* __restrict__ og)
{
    __shared__ u16  SB[9216];          // xn [64][136] (8704) / wave regions 4x2304
    __shared__ float gln[128], bln[128];

    const int t   = threadIdx.x;
    const int bid = blockIdx.x;
    const int a0  = (bid >> 6) << 3;
    const int b0  = (bid & 63) << 3;
    const int w = t >> 6, l = t & 63;
    const int lrow = l & 15, g = l >> 4;
    const int nb = w * 32;
    const int orow = g << 2;
    const int kb = a0 >> 3;

    // ---- prologue: x loads, LN stats, normalize into SB-as-xn ----
    const int r = t >> 2, q = t & 3;
    const int aa = a0 + (r & 7), bb = b0 + (r >> 3);
    const float4* xrow = reinterpret_cast<const float4*>(x + ((size_t)aa * Ns + bb) * Dd);
    float4 xv[8];
#pragma unroll
    for (int i2 = 0; i2 < 8; ++i2) xv[i2] = xrow[q + 4 * i2];
    if (t < 128){ gln[t] = g_ln[t]; bln[t] = b_ln[t]; }

    float s1 = 0.f, s2 = 0.f;
#pragma unroll
    for (int i2 = 0; i2 < 8; ++i2){
        float4 v = xv[i2];
        s1 += v.x + v.y + v.z + v.w;
        s2 += v.x * v.x + v.y * v.y + v.z * v.z + v.w * v.w;
    }
    s1 += __shfl_xor(s1, 1); s1 += __shfl_xor(s1, 2);
    s2 += __shfl_xor(s2, 1); s2 += __shfl_xor(s2, 2);
    const float mm  = s1 * (1.0f / 128.0f);
    const float rsv = rsqrtf(s2 * (1.0f / 128.0f) - mm * mm + EPSV);
    __syncthreads();                   // (1) gln/bln ready
#pragma unroll
    for (int i2 = 0; i2 < 8; ++i2){
        const int d = (q + 4 * i2) * 4;
        ushort4 o;
        o.x = f2bf((xv[i2].x - mm) * rsv * gln[d + 0] + bln[d + 0]);
        o.y = f2bf((xv[i2].y - mm) * rsv * gln[d + 1] + bln[d + 1]);
        o.z = f2bf((xv[i2].z - mm) * rsv * gln[d + 2] + bln[d + 2]);
        o.w = f2bf((xv[i2].w - mm) * rsv * gln[d + 3] + bln[d + 3]);
        *reinterpret_cast<ushort4*>(&SB[r * 136 + d]) = o;
    }
    __syncthreads();                   // (2) xn ready

    // ---- A-fragments once (R4-verified) ----
    bf16x8 af[4][4];
#pragma unroll
    for (int ks = 0; ks < 4; ++ks)
#pragma unroll
        for (int rf = 0; rf < 4; ++rf)
            af[ks][rf] = *reinterpret_cast<const bf16x8*>(&SB[(rf * 16 + lrow) * 136 + ks * 32 + g * 8]);
    __syncthreads();                   // (3) all af reads done; SB free

    u16* SBw = &SB[w * 2304];          // wave-private region
    const f32x4 zero4 = {0.f, 0.f, 0.f, 0.f};
    f32x4 aV[4], aG[4];

    auto GEMM1 = [&](const u16* WV, const u16* WG, int cf){
        const int col = nb + cf * 16 + lrow;
#pragma unroll
        for (int rf = 0; rf < 4; ++rf){ aV[rf] = zero4; aG[rf] = zero4; }
#pragma unroll
        for (int ks = 0; ks < 4; ++ks){
            bf16x8 bv = *reinterpret_cast<const bf16x8*>(WV + (size_t)col * 128 + ks * 32 + g * 8);
            bf16x8 bg = *reinterpret_cast<const bf16x8*>(WG + (size_t)col * 128 + ks * 32 + g * 8);
#pragma unroll
            for (int rf = 0; rf < 4; ++rf)
                aV[rf] = __builtin_amdgcn_mfma_f32_16x16x32_bf16(af[ks][rf], bv, aV[rf], 0, 0, 0);
#pragma unroll
            for (int rf = 0; rf < 4; ++rf)
                aG[rf] = __builtin_amdgcn_mfma_f32_16x16x32_bf16(af[ks][rf], bg, aG[rf], 0, 0, 0);
        }
    };
    auto STW = [&](const float* bV, const float* bG, int cf){
        const int cl2 = cf * 16 + lrow;
        const int col = nb + cl2;
        const float bVv = bV[col], bGv = bG[col];
#pragma unroll
        for (int rf = 0; rf < 4; ++rf){
            ushort4 pk;
#pragma unroll
            for (int j = 0; j < 4; ++j){
                const float vv = aV[rf][j] + bVv;
                const float gg = aG[rf][j] + bGv;
                ((u16*)&pk)[j] = f2bf(sigmoidf_(gg) * vv);
            }
            *reinterpret_cast<ushort4*>(&SBw[cl2 * 68 + rf * 16 + orow]) = pk;
        }
    };
    auto STORE = [&](u16* dst){
#pragma unroll
        for (int it = 0; it < 4; ++it){
            const int cl2 = it * 8 + (l >> 3);
            const int s   = l & 7;
            int4 v = *reinterpret_cast<const int4*>(&SBw[cl2 * 68 + s * 8]);
            *reinterpret_cast<int4*>(dst + (((size_t)(nb + cl2) * 64 + kb) * Ns + b0) * 8 + s * 8) = v;
        }
    };

    // ---- L/R pipeline (wave-private; fences order same-wave LDS reuse) ----
    GEMM1(Wt,             Wt + 16384,     0); STW(bl, blg, 0);
    GEMM1(Wt,             Wt + 16384,     1); STW(bl, blg, 1);
    LDS_FENCE;
    STORE(left);
    LDS_FENCE;
    GEMM1(Wt + 2 * 16384, Wt + 3 * 16384, 0); STW(br, brg, 0);
    GEMM1(Wt + 2 * 16384, Wt + 3 * 16384, 1); STW(br, brg, 1);
    LDS_FENCE;
    STORE(right);
    LDS_FENCE;                         // readback done before og overwrites region

    // ---- og phase: wave-private staging (stride 36), b64 readback, 64B stores ----
    {
        const u16* WOG = Wt + (size_t)4 * 16384;
#pragma unroll 1
        for (int cf = 0; cf < 2; ++cf){
            const int cl2 = cf * 16 + lrow;
            const int col = nb + cl2;
#pragma unroll
            for (int rf = 0; rf < 4; ++rf) aV[rf] = zero4;
#pragma unroll
            for (int ks = 0; ks < 4; ++ks){
                bf16x8 bv = *reinterpret_cast<const bf16x8*>(WOG + (size_t)col * 128 + ks * 32 + g * 8);
#pragma unroll
                for (int rf = 0; rf < 4; ++rf)
                    aV[rf] = __builtin_amdgcn_mfma_f32_16x16x32_bf16(af[ks][rf], bv, aV[rf], 0, 0, 0);
            }
            const float bOv = bog[col];
#pragma unroll
            for (int rf = 0; rf < 4; ++rf)
#pragma unroll
                for (int j = 0; j < 4; ++j){
                    const int row = rf * 16 + orow + j;
                    SBw[row * 36 + cl2] = f2bf(sigmoidf_(aV[rf][j] + bOv));
                }
        }
        LDS_FENCE;
        // readback: lane l owns row l; 8 x b64 (2-way-spread banks), 64B global chunk
        u16* dstp = og + (((size_t)(a0 + (l & 7)) * Ns) + (b0 + (l >> 3))) * Cc + nb;
#pragma unroll
        for (int s = 0; s < 4; ++s){
            int2 lo = *reinterpret_cast<const int2*>(&SBw[l * 36 + s * 8]);
            *reinterpret_cast<int2*>(dstp + s * 8)     = lo;
        }
#pragma unroll
        for (int s = 0; s < 4; ++s){
            int2 hi = *reinterpret_cast<const int2*>(&SBw[l * 36 + s * 8 + 4]);
            *reinterpret_cast<int2*>(dstp + s * 8 + 4) = hi;
        }
    }
}

// ---------------------------------------------------------------------------
// K2: om[c][i][j] = sum_k left[c][k][i] * right[c][k][j]   (per-channel GEMM)
// 1-D grid 2048, XCD-swizzled so each XCD owns 16 whole channels.  (frozen)
// ---------------------------------------------------------------------------
#define K2_LOAD(AF, BF, KS) do {                                                    \
    const size_t kbrow_ = (size_t)((KS) * 4 + lkb) * Ns;                            \
    _Pragma("unroll") for (int rf = 0; rf < 4; ++rf)                                \
        AF[rf] = *reinterpret_cast<const bf16x8*>(Lc + (kbrow_ + ib + rf * 16 + lrow) * 8); \
    _Pragma("unroll") for (int cf = 0; cf < 4; ++cf)                                \
        BF[cf] = *reinterpret_cast<const bf16x8*>(Rc + (kbrow_ + jb + cf * 16 + lrow) * 8); \
} while (0)

#define K2_MM(AF, BF) do {                                                          \
    _Pragma("unroll") for (int rf = 0; rf < 4; ++rf)                                \
    _Pragma("unroll") for (int cf = 0; cf < 4; ++cf)                                \
        acc[rf][cf] = __builtin_amdgcn_mfma_f32_16x16x32_bf16(AF[rf], BF[cf], acc[rf][cf], 0, 0, 0); \
} while (0)

__global__ __launch_bounds__(256) void k2(const u16* __restrict__ left,
                                          const u16* __restrict__ right,
                                          u16* __restrict__ om)
{
    __shared__ u16 sO[128][136];
    const int bid = blockIdx.x;
    const int xcd = bid & 7, idxx = bid >> 3;
    const int virt = xcd * 256 + idxx;
    const int c    = virt >> 4;
    const int tile = virt & 15;
    const int iy = tile >> 2, jx = tile & 3;
    const int t = threadIdx.x, w = t >> 6, l = t & 63;
    const int wr = w >> 1, wc = w & 1;
    const int ib = iy * 128 + wr * 64;
    const int jb = jx * 128 + wc * 64;
    const int lrow = l & 15, lkb = l >> 4;
    const u16* Lc = left  + (size_t)c * (Ns * Ns);
    const u16* Rc = right + (size_t)c * (Ns * Ns);
    const f32x4 zero4 = {0.f, 0.f, 0.f, 0.f};
    f32x4 acc[4][4];
#pragma unroll
    for (int rf = 0; rf < 4; ++rf)
#pragma unroll
        for (int cf = 0; cf < 4; ++cf) acc[rf][cf] = zero4;

    bf16x8 a0f[4], b0f[4], a1f[4], b1f[4];
    K2_LOAD(a0f, b0f, 0);
#pragma unroll
    for (int ks = 0; ks < 16; ks += 2){
        K2_LOAD(a1f, b1f, ks + 1);
        K2_MM(a0f, b0f);
        if (ks + 2 < 16) K2_LOAD(a0f, b0f, ks + 2);
        K2_MM(a1f, b1f);
    }

    const int orow = (l >> 4) << 2;
#pragma unroll
    for (int rf = 0; rf < 4; ++rf)
#pragma unroll
        for (int j2 = 0; j2 < 4; ++j2){
            const int rloc = wr * 64 + rf * 16 + orow + j2;
#pragma unroll
            for (int cf = 0; cf < 4; ++cf)
                sO[rloc][wc * 64 + cf * 16 + lrow] = f2bf(acc[rf][cf][j2]);
        }
    __syncthreads();
    u16* obase = om + (size_t)c * Ns * Ns + (size_t)(iy * 128) * Ns + jx * 128;
#pragma unroll
    for (int s = 0; s < 8; ++s){
        const int gg = s * 256 + t;
        const int row = gg >> 4, co = (gg & 15) * 8;
        int4 v = *reinterpret_cast<const int4*>(&sO[row][co]);
        *reinterpret_cast<int4*>(obase + (size_t)row * Ns + co) = v;
    }
}

// ---------------------------------------------------------------------------
// K3: final = sigmoid(og) * (LN_c(out_mid) @ Wo + bo), fp32 out  (R8-verified)
// ---------------------------------------------------------------------------
__global__ __launch_bounds__(256) void k3(
    const u16* __restrict__ om, const u16* __restrict__ og, const u16* __restrict__ Wt,
    const float* __restrict__ g2, const float* __restrict__ b2, const float* __restrict__ bo,
    float* __restrict__ out)
{
    __shared__ char smem[34816];
    u16* X = reinterpret_cast<u16*>(smem);
    u16* O = reinterpret_cast<u16*>(smem) + 8704;
    __shared__ float sg2[128], sb2[128];
    const int i  = blockIdx.y;
    const int j0 = blockIdx.x * 64;
    const int t  = threadIdx.x;
    if (t < 128){ sg2[t] = g2[t]; sb2[t] = b2[t]; }
    {
        const int c = t >> 1, jh = (t & 1) * 32;
        const u16* src = om + (size_t)c * Ns * Ns + (size_t)i * Ns + j0 + jh;
#pragma unroll
        for (int s = 0; s < 8; ++s){
            ushort4 v = reinterpret_cast<const ushort4*>(src)[s];
            const int jj = jh + s * 4;
            X[(jj + 0) * 136 + c] = v.x; X[(jj + 1) * 136 + c] = v.y;
            X[(jj + 2) * 136 + c] = v.z; X[(jj + 3) * 136 + c] = v.w;
        }
    }
    {
        const int jj = t >> 2, qq = t & 3;
        const u16* src = og + ((size_t)i * Ns + j0 + jj) * Cc + qq * 32;
#pragma unroll
        for (int s = 0; s < 4; ++s)
            *reinterpret_cast<int4*>(&O[jj * 136 + qq * 32 + s * 8]) = reinterpret_cast<const int4*>(src)[s];
    }
    __syncthreads();
    const int r = t >> 2, q = t & 3;
    {
        float s1 = 0.f, s2v = 0.f;
#pragma unroll
        for (int e = 0; e < 32; ++e){
            const float v = bf2f(X[r * 136 + q * 32 + e]);
            s1 += v; s2v += v * v;
        }
        s1  += __shfl_xor(s1, 1);  s1  += __shfl_xor(s1, 2);
        s2v += __shfl_xor(s2v, 1); s2v += __shfl_xor(s2v, 2);
        const float mm  = s1 * (1.0f / 128.0f);
        const float rsv = rsqrtf(s2v * (1.0f / 128.0f) - mm * mm + EPSV);
#pragma unroll
        for (int e = 0; e < 32; ++e){
            const int cc = q * 32 + e;
            const float v = bf2f(X[r * 136 + cc]);
            X[r * 136 + cc] = f2bf((v - mm) * rsv * sg2[cc] + sb2[cc]);
        }
    }
    __syncthreads();
    const int w = t >> 6, l = t & 63;
    const int lrow = l & 15, lk = (l >> 4) << 3, nbv = w * 32, orow = (l >> 4) << 2;
    const u16* WO = Wt + (size_t)5 * 16384;
    const f32x4 zero4 = {0.f, 0.f, 0.f, 0.f};
    f32x4 acc[4][2];
#pragma unroll
    for (int rf = 0; rf < 4; ++rf)
#pragma unroll
        for (int cf = 0; cf < 2; ++cf) acc[rf][cf] = zero4;
#pragma unroll
    for (int ks = 0; ks < 4; ++ks){
        const int k0 = ks * 32 + lk;
        bf16x8 af[4];
#pragma unroll
        for (int rf = 0; rf < 4; ++rf)
            af[rf] = *reinterpret_cast<const bf16x8*>(&X[(rf * 16 + lrow) * 136 + k0]);
#pragma unroll
        for (int cf = 0; cf < 2; ++cf){
            bf16x8 bv = *reinterpret_cast<const bf16x8*>(WO + (size_t)(nbv + cf * 16 + lrow) * 128 + k0);
#pragma unroll
            for (int rf = 0; rf < 4; ++rf)
                acc[rf][cf] = __builtin_amdgcn_mfma_f32_16x16x32_bf16(af[rf], bv, acc[rf][cf], 0, 0, 0);
        }
    }
    float gv[2][4][4];
#pragma unroll
    for (int cf = 0; cf < 2; ++cf){
        const int cg = nbv + cf * 16 + lrow;
        const float bov = bo[cg];
#pragma unroll
        for (int rf = 0; rf < 4; ++rf)
#pragma unroll
            for (int j = 0; j < 4; ++j){
                const int row = rf * 16 + orow + j;
                gv[cf][rf][j] = bf2f(O[row * 136 + cg]) * (acc[rf][cf][j] + bov);
            }
    }
    __syncthreads();
    float* sF = reinterpret_cast<float*>(smem);
#pragma unroll
    for (int cf = 0; cf < 2; ++cf){
        const int cg = nbv + cf * 16 + lrow;
#pragma unroll
        for (int rf = 0; rf < 4; ++rf)
#pragma unroll
            for (int j = 0; j < 4; ++j){
                const int row = rf * 16 + orow + j;
                sF[row * 128 + cg] = gv[cf][rf][j];
            }
    }
    __syncthreads();
    const float4* sF4 = reinterpret_cast<const float4*>(smem);
    float* obase = out + ((size_t)i * Ns + j0) * Cc;
#pragma unroll
    for (int s = 0; s < 8; ++s){
        const int gg = s * 256 + t;
        const int row = gg >> 5, co = (gg & 31) * 4;
        float4 v = sF4[gg];
        *reinterpret_cast<float4*>(obase + (size_t)row * Cc + co) = v;
    }
}

// ---------------------------------------------------------------------------
extern "C" void kernel_launch(void* const* d_in, const int* in_sizes, int n_in,
                              void* d_out, int out_size, void* d_ws, size_t ws_size,
                              hipStream_t stream)
{
    const float* x    = (const float*)d_in[0];
    const float* ling = (const float*)d_in[1];
    const float* linb = (const float*)d_in[2];
    const float* loutg= (const float*)d_in[3];
    const float* loutb= (const float*)d_in[4];
    const float* Wl   = (const float*)d_in[5];
    const float* bl   = (const float*)d_in[6];
    const float* Wr   = (const float*)d_in[7];
    const float* br   = (const float*)d_in[8];
    const float* Wo   = (const float*)d_in[9];
    const float* bo   = (const float*)d_in[10];
    const float* Wlg  = (const float*)d_in[11];
    const float* blg  = (const float*)d_in[12];
    const float* Wrg  = (const float*)d_in[13];
    const float* brg  = (const float*)d_in[14];
    const float* Wog  = (const float*)d_in[15];
    const float* bog  = (const float*)d_in[16];

    char* ws = (char*)d_ws;
    u16* Wt = (u16*)ws;
    const size_t off = 256 * 1024;
    const size_t SZ  = (size_t)33554432 * 2;   // 64 MiB per bf16 tensor
    u16* left  = (u16*)(ws + off);
    u16* right = (u16*)(ws + off + SZ);
    u16* og    = (u16*)(ws + off + 2 * SZ);
    u16* om    = (u16*)(ws + off + 3 * SZ);

    hipLaunchKernelGGL(k_prep, dim3(384), dim3(256), 0, stream, Wl, Wlg, Wr, Wrg, Wog, Wo, Wt);
    hipLaunchKernelGGL(k1, dim3(4096), dim3(256), 0, stream,
                       x, ling, linb, Wt, bl, blg, br, brg, bog, left, right, og);
    hipLaunchKernelGGL(k2, dim3(2048), dim3(256), 0, stream, left, right, om);
    hipLaunchKernelGGL(k3, dim3(8, 512), dim3(256), 0, stream, om, og, Wt, loutg, loutb, bo, (float*)d_out);
}